// Round 5
// baseline (287.804 us; speedup 1.0000x reference)
//
#include <hip/hip_runtime.h>

using uint = unsigned int;
using ushort = unsigned short;

typedef __attribute__((ext_vector_type(8))) short bf16x8;
typedef __attribute__((ext_vector_type(4))) short bf16x4;
typedef __attribute__((ext_vector_type(4))) float f32x4;

#define ADMM_ITERS 100
#define RHO_C 1.0f
#define SIGMA_C 1e-6f

__device__ inline ushort f2bf(float f) {
  union { float f; uint u; } c; c.f = f;
  uint u = c.u;
  uint r = (u + 0x7fffu + ((u >> 16) & 1u)) >> 16;
  return (ushort)r;
}

__device__ inline void gload_lds16(const void* g, void* l) {
  __builtin_amdgcn_global_load_lds(
      (const __attribute__((address_space(1))) void*)g,
      (__attribute__((address_space(3))) void*)l, 16, 0, 0);
}

// Split 8 f32 -> hi/lo bf16x8 by TRUNCATION (hi = mantissa-masked; lo = exact
// residual, truncated). Residual error ~2^-16 relative.
__device__ inline void splitPack(const float* x, bf16x8& hi, bf16x8& lo) {
#pragma unroll
  for (int j = 0; j < 8; ++j) {
    uint b = __float_as_uint(x[j]);
    uint hb = b & 0xffff0000u;
    float lf = x[j] - __uint_as_float(hb);
    hi[j] = (short)(b >> 16);
    lo[j] = (short)(__float_as_uint(lf) >> 16);
  }
}

// 4 f32 -> two hi-pair dwords + two lo-pair dwords (truncation split, even
// element in low 16 bits). Bit-identical values to splitPack.
__device__ inline void packPairs(const f32x4& x, uint& h0, uint& h1,
                                 uint& l0, uint& l1) {
  uint b0 = __float_as_uint(x[0]), b1 = __float_as_uint(x[1]);
  uint b2 = __float_as_uint(x[2]), b3 = __float_as_uint(x[3]);
  float r0 = x[0] - __uint_as_float(b0 & 0xffff0000u);
  float r1 = x[1] - __uint_as_float(b1 & 0xffff0000u);
  float r2 = x[2] - __uint_as_float(b2 & 0xffff0000u);
  float r3 = x[3] - __uint_as_float(b3 & 0xffff0000u);
  h0 = __builtin_amdgcn_perm(b1, b0, 0x07060302u);
  h1 = __builtin_amdgcn_perm(b3, b2, 0x07060302u);
  l0 = __builtin_amdgcn_perm(__float_as_uint(r1), __float_as_uint(r0), 0x07060302u);
  l1 = __builtin_amdgcn_perm(__float_as_uint(r3), __float_as_uint(r2), 0x07060302u);
}

// ---------------------------------------------------------------------------
// prep bodies (fused into prep_all)
// ---------------------------------------------------------------------------
__device__ void transpose_body(const float* __restrict__ in, ushort* __restrict__ out,
                               int R, int C, int Cout, int bx, int by, int tid) {
  __shared__ float t[32][33];
  const int c0 = bx * 32, r0 = by * 32;
  const int tx = tid & 31, ty = tid >> 5;
  for (int rr = ty; rr < 32; rr += 8) {
    int r = r0 + rr, c = c0 + tx;
    float v = 0.0f;
    if (r < R && c < C) v = in[(long)r * C + c];
    t[rr][tx] = v;
  }
  __syncthreads();
  for (int rr = ty; rr < 32; rr += 8) {
    int c = c0 + rr, r = r0 + tx;
    if (c < Cout && r < R) out[(long)c * R + r] = f2bf(t[tx][rr]);
  }
}

// ADMM setup -> MFMA operand form. (unchanged; see earlier rounds)
__device__ void setup_body(const float* __restrict__ Aeq, const float* __restrict__ beq,
                           const float* __restrict__ A, const float* __restrict__ b,
                           const float* __restrict__ ub, const float* __restrict__ lb,
                           ushort* __restrict__ Th, ushort* __restrict__ Tl,
                           ushort* __restrict__ T0h, ushort* __restrict__ T0l,
                           float* __restrict__ blp, float* __restrict__ bup, int t) {
  __shared__ float Aug[24][48];
  __shared__ float A12[12 * 24];
  __shared__ float fac[24];
  __shared__ float Tx[24][36];
  for (int i = t; i < 48 * 64; i += 256) { Th[i] = 0; Tl[i] = 0; }
  for (int i = t; i < 48 * 32; i += 256) { T0h[i] = 0; T0l[i] = 0; }
  if (t < 96)  A12[t] = Aeq[t];
  if (t < 192) A12[96 + t] = A[t];
  __syncthreads();
  for (int idx = t; idx < 576; idx += 256) {
    int j = idx / 24, k = idx % 24;
    float s = (j == k) ? (1.0f + SIGMA_C + 2.0f * RHO_C) : 0.0f;
    for (int r = 0; r < 12; ++r) s += RHO_C * A12[r * 24 + j] * A12[r * 24 + k];
    Aug[j][k] = s;
    Aug[j][24 + k] = (j == k) ? 1.0f : 0.0f;
  }
  __syncthreads();
  for (int p = 0; p < 24; ++p) {
    float rp = 1.0f / Aug[p][p];
    if (t < 24) fac[t] = Aug[t][p];
    __syncthreads();
    if (t < 48) Aug[p][t] *= rp;
    __syncthreads();
    for (int idx = t; idx < 24 * 48; idx += 256) {
      int r = idx / 48, c = idx % 48;
      if (r != p) Aug[r][c] -= fac[r] * Aug[p][c];
    }
    __syncthreads();
  }
  auto splitStore = [](ushort* hp, ushort* lp, int i, float v) {
    ushort hs = f2bf(v);
    float hf = __uint_as_float(((uint)hs) << 16);
    ushort ls = f2bf(v - hf);
    hp[i] = hs; lp[i] = ls;
  };
  for (int idx = t; idx < 24 * 36; idx += 256) {
    int n = idx / 36, k = idx % 36;
    float v;
    if (k < 24) v = 2.0f * Aug[n][24 + k];
    else {
      v = 0.0f;
      for (int j = 0; j < 24; ++j) v += Aug[n][24 + j] * A12[(k - 24) * 24 + j];
    }
    Tx[n][k] = v;
    splitStore(Th, Tl, n * 64 + k, v);
  }
  __syncthreads();
  for (int idx = t; idx < 12 * 36; idx += 256) {
    int m = idx / 36, k = idx % 36;
    float v = 0.0f;
    for (int j = 0; j < 24; ++j) v += A12[m * 24 + j] * Tx[j][k];
    splitStore(Th, Tl, (24 + m) * 64 + k, v);
  }
  for (int idx = t; idx < 36 * 24; idx += 256) {
    int n = idx / 24, k = idx % 24;
    float v;
    if (n < 24) v = Aug[n][24 + k];
    else {
      v = 0.0f;
      for (int j = 0; j < 24; ++j) v += A12[(n - 24) * 24 + j] * Aug[j][24 + k];
    }
    splitStore(T0h, T0l, n * 32 + k, v);
  }
  if (t < 48) {
    float lv, uv;
    if (t < 24)      { lv = lb[t]; uv = ub[t]; }
    else if (t < 28) { lv = beq[t - 24]; uv = lv; }
    else if (t < 36) { lv = -1e30f; uv = b[t - 28]; }
    else             { lv = -1e30f; uv = 1e30f; }
    blp[t] = lv; bup[t] = uv;
  }
}

// Fused prep: [0,nConv) convert | [+512) W1T | [+1024) W2T | [+32) W3T | [1) setup
__global__ void prep_all(
    const float* __restrict__ state, ushort* __restrict__ stateB, int n4,
    const float* __restrict__ W1, ushort* __restrict__ W1T,
    const float* __restrict__ W2, ushort* __restrict__ W2T,
    const float* __restrict__ W3, ushort* __restrict__ W3T,
    const float* __restrict__ Aeq, const float* __restrict__ beq,
    const float* __restrict__ A, const float* __restrict__ b,
    const float* __restrict__ ub, const float* __restrict__ lb,
    ushort* __restrict__ Th, ushort* __restrict__ Tl,
    ushort* __restrict__ T0h, ushort* __restrict__ T0l,
    float* __restrict__ blp, float* __restrict__ bup) {
  const int nConv = n4 >> 8;
  int bb = blockIdx.x;
  if (bb < nConv) {
    int i = bb * 256 + threadIdx.x;
    if (i < n4) {
      float4 v = ((const float4*)state)[i];
      uint2 p;
      p.x = (uint)f2bf(v.x) | ((uint)f2bf(v.y) << 16);
      p.y = (uint)f2bf(v.z) | ((uint)f2bf(v.w) << 16);
      ((uint2*)stateB)[i] = p;
    }
    return;
  }
  bb -= nConv;
  if (bb < 512)  { transpose_body(W1, W1T, 512, 1024, 1024, bb & 31, bb >> 5, threadIdx.x); return; }
  bb -= 512;
  if (bb < 1024) { transpose_body(W2, W2T, 1024, 1024, 1024, bb & 31, bb >> 5, threadIdx.x); return; }
  bb -= 1024;
  if (bb < 32)   { transpose_body(W3, W3T, 1024, 24, 32, 0, bb, threadIdx.x); return; }
  setup_body(Aeq, beq, A, b, ub, lb, Th, Tl, T0h, T0l, blp, bup, threadIdx.x);
}

// ---------------------------------------------------------------------------
// bf16 GEMM, C = A[M,K] * Bt[N,K]^T — m97-style staging (skinny final layer).
// ---------------------------------------------------------------------------
template<int BM, int BN, int WM, int WN, int TM, int TN, int MODE>
__global__ __launch_bounds__(256) void gemm_bt(
    const ushort* __restrict__ A, const ushort* __restrict__ Bt,
    const float* __restrict__ bias, void* __restrict__ Cout_,
    int K, int ldc, int nvalid) {
  __shared__ char lds[(BM + BN) * 64];
  char* ldsA = lds;
  char* ldsB = lds + BM * 64;

  const int tid = threadIdx.x;
  const int wave = tid >> 6;
  const int lane = tid & 63;
  const int blockM = blockIdx.y * BM;
  const int blockN = blockIdx.x * BN;
  const int wm = (wave / WN) * (TM * 16);
  const int wn = (wave % WN) * (TN * 16);

  f32x4 acc[TM][TN] = {};

  const int l15 = lane & 15;
  const int kq = lane >> 4;
  constexpr int AI = BM / 16;
  constexpr int TOT = (BM + BN) / 16;
  const int srow = lane >> 2;
  const int kb = (lane & 3) ^ ((srow >> 1) & 3);

  for (int k0 = 0; k0 < K; k0 += 32) {
    for (int inst = wave; inst < TOT; inst += 4) {
      const bool isA = inst < AI;
      const int i = isA ? inst : inst - AI;
      const ushort* gp = (isA ? A : Bt)
          + (long)((isA ? blockM : blockN) + i * 16 + srow) * K + (k0 + kb * 8);
      char* lp = (isA ? ldsA : ldsB) + i * 1024;
      gload_lds16(gp, lp);
    }
    __syncthreads();

    bf16x8 af[TM], bfr[TN];
#pragma unroll
    for (int i = 0; i < TM; ++i) {
      int r = wm + i * 16 + l15;
      int ch = kq ^ ((r >> 1) & 3);
      af[i] = *(const bf16x8*)(ldsA + r * 64 + ch * 16);
    }
#pragma unroll
    for (int j = 0; j < TN; ++j) {
      int r = wn + j * 16 + l15;
      int ch = kq ^ ((r >> 1) & 3);
      bfr[j] = *(const bf16x8*)(ldsB + r * 64 + ch * 16);
    }
#pragma unroll
    for (int i = 0; i < TM; ++i)
#pragma unroll
      for (int j = 0; j < TN; ++j)
        acc[i][j] = __builtin_amdgcn_mfma_f32_16x16x32_bf16(af[i], bfr[j], acc[i][j], 0, 0, 0);
    __syncthreads();
  }

  const int ro = lane >> 4;
#pragma unroll
  for (int i = 0; i < TM; ++i) {
#pragma unroll
    for (int j = 0; j < TN; ++j) {
      const int col = blockN + wn + j * 16 + l15;
      float bv;
      if (MODE == 0) bv = bias[col];
      else bv = (col < nvalid) ? bias[col] : 0.0f;
#pragma unroll
      for (int r = 0; r < 4; ++r) {
        const int row = blockM + wm + i * 16 + ro * 4 + r;
        float v = acc[i][j][r] + bv;
        if (MODE == 0) {
          v = fmaxf(v, 0.0f);
          ((ushort*)Cout_)[(long)row * ldc + col] = f2bf(v);
        } else {
          if (col < nvalid) ((float*)Cout_)[(long)row * ldc + col] = v;
        }
      }
    }
  }
}

// ---------------------------------------------------------------------------
// 256x256 8-phase bf16 GEMM (T1+T2+T3+T4+T5) — unchanged.
// ---------------------------------------------------------------------------
#define GEMM8P_QUAD(MI0, NJ0)                                                 \
  _Pragma("unroll") for (int mi_ = 0; mi_ < 4; ++mi_)                         \
  _Pragma("unroll") for (int nj_ = 0; nj_ < 2; ++nj_)                         \
  _Pragma("unroll") for (int kk_ = 0; kk_ < 2; ++kk_)                         \
    acc[(MI0) + mi_][(NJ0) + nj_] = __builtin_amdgcn_mfma_f32_16x16x32_bf16(  \
        aF[mi_][kk_], bF[(NJ0) + nj_][kk_], acc[(MI0) + mi_][(NJ0) + nj_],    \
        0, 0, 0);

#define GEMM8P_SYNC_PRE()                              \
  __builtin_amdgcn_s_barrier();                        \
  asm volatile("s_waitcnt lgkmcnt(0)" ::: "memory");   \
  __builtin_amdgcn_sched_barrier(0);                   \
  __builtin_amdgcn_s_setprio(1);

#define GEMM8P_SYNC_POST()                             \
  __builtin_amdgcn_s_setprio(0);                       \
  __builtin_amdgcn_s_barrier();

__global__ __launch_bounds__(512, 2) void gemm8p(
    const ushort* __restrict__ A, const ushort* __restrict__ Bt,
    const float* __restrict__ bias, ushort* __restrict__ Cout,
    int K, int ldc, int nblk_n) {
  __shared__ __align__(16) char ldsc[131072];   // [2 buf][A 32K | B 32K]

  const int nwg = gridDim.x;
  const int bid = blockIdx.x;
  const int swz = (bid & 7) * (nwg >> 3) + (bid >> 3);
  const int blockM = (swz / nblk_n) * 256;
  const int blockN = (swz % nblk_n) * 256;

  const int tid = threadIdx.x;
  const int wave = tid >> 6;
  const int lane = tid & 63;
  const int l15 = lane & 15;
  const int q = lane >> 4;
  const int wm = (wave >> 2) * 128;
  const int wn = (wave & 3) * 64;
  const int nt = K >> 6;

  f32x4 acc[8][4] = {};

  auto stage = [&](int ts, int h) {
    if (ts >= nt) return;
    char* base = ldsc + ((ts & 1) << 16) + (h << 14);
#pragma unroll
    for (int j = 0; j < 2; ++j) {
      const int idx = wave * 64 + j * 512 + lane;
      const int row = idx >> 3;
      const int cs = (idx & 7) ^ (row & 7);
      const ushort* gp =
          (h < 2 ? A + (long)(blockM + ((h & 1) << 7) + row) * K
                 : Bt + (long)(blockN + ((h & 1) << 7) + row) * K)
          + (ts << 6) + cs * 8;
      gload_lds16(gp, base + ((wave * 64 + j * 512) << 4));
    }
  };
  auto dsA = [&](int cb, int mi, int kk) {
    const int r = wm + mi * 16 + l15;
    const int cs = (kk * 4 + q) ^ (r & 7);
    return *(const bf16x8*)(ldsc + (cb << 16) + r * 128 + cs * 16);
  };
  auto dsB = [&](int cb, int nj, int kk) {
    const int r = wn + nj * 16 + l15;
    const int cs = (kk * 4 + q) ^ (r & 7);
    return *(const bf16x8*)(ldsc + (cb << 16) + 32768 + r * 128 + cs * 16);
  };

  stage(0, 0); stage(0, 1); stage(0, 2); stage(0, 3);
  stage(1, 0);
  asm volatile("s_waitcnt vmcnt(2)" ::: "memory");
  __builtin_amdgcn_s_barrier();

  bf16x8 aF[4][2], bF[4][2];
#pragma unroll 1
  for (int t = 0; t < nt; ++t) {
    const int cb = t & 1;
#pragma unroll
    for (int mi = 0; mi < 4; ++mi)
#pragma unroll
      for (int kk = 0; kk < 2; ++kk) aF[mi][kk] = dsA(cb, mi, kk);
#pragma unroll
    for (int nj = 0; nj < 2; ++nj)
#pragma unroll
      for (int kk = 0; kk < 2; ++kk) bF[nj][kk] = dsB(cb, nj, kk);
    stage(t + 1, 1);
    GEMM8P_SYNC_PRE();
    GEMM8P_QUAD(0, 0);
    GEMM8P_SYNC_POST();
#pragma unroll
    for (int nj = 2; nj < 4; ++nj)
#pragma unroll
      for (int kk = 0; kk < 2; ++kk) bF[nj][kk] = dsB(cb, nj, kk);
    stage(t + 1, 2);
    GEMM8P_SYNC_PRE();
    GEMM8P_QUAD(0, 2);
    GEMM8P_SYNC_POST();
#pragma unroll
    for (int mi = 0; mi < 4; ++mi)
#pragma unroll
      for (int kk = 0; kk < 2; ++kk) aF[mi][kk] = dsA(cb, 4 + mi, kk);
    stage(t + 1, 3);
    GEMM8P_SYNC_PRE();
    GEMM8P_QUAD(4, 2);
    GEMM8P_SYNC_POST();
    stage(t + 2, 0);
    if (t + 2 < nt) { asm volatile("s_waitcnt vmcnt(2)" ::: "memory"); }
    else            { asm volatile("s_waitcnt vmcnt(0)" ::: "memory"); }
    __builtin_amdgcn_s_barrier();
    __builtin_amdgcn_s_setprio(1);
    GEMM8P_QUAD(4, 0);
    GEMM8P_SYNC_POST();
  }

#pragma unroll
  for (int mi = 0; mi < 8; ++mi) {
#pragma unroll
    for (int nj = 0; nj < 4; ++nj) {
      const int col = blockN + wn + nj * 16 + l15;
      const float bv = bias[col];
#pragma unroll
      for (int r = 0; r < 4; ++r) {
        const int row = blockM + wm + mi * 16 + q * 4 + r;
        float v = acc[mi][nj][r] + bv;
        v = fmaxf(v, 0.0f);
        Cout[(long)row * ldc + col] = f2bf(v);
      }
    }
  }
}

// ---------------------------------------------------------------------------
// ADMM via MFMA (round-5 rewrite).
// EVIDENCE (r1-r4): K16 register-feedback variants all ~1500 cy/iter; the
// K32 LDS-transpose variant (r1) was FASTER (1340) despite untuned LDS ->
// the legacy 16x16x16bf16_1k MFMA is slow on gfx950 + VALU<->MFMA crossing
// tax. This round: back to measured-fast 16x16x32 MFMAs (18/iter, 6-deep
// C-chains round-robined over 3 tiles) with a LEAN packed-bf16 LDS
// transpose: pack u -> bf16 hi/lo pairs BEFORE store (6 ds_write_b64 +
// 4 ds_read_b128 per iter, no barriers: DS ops are in-order per wave).
// Layout: per wave, hi buf [16 rows(l15)][36 dw] + lo buf at +576 dw.
// Pair P'=8t+2q'+p (rows 16t+4q'+2p,+1) stored at dword 4*(Q^(l15&7))+w,
// Q=P'>>2=2t+(q'>>1), w=P'&3. Read chunk c: b128 at 4*((4c+q)^(l15&7)):
// dword m <- Q=4c+q, w=m <- t=2c+(q>>1), q'=2(q&1)+(m>>1), p=m&1 ->
// rows 32c+16(q>>1)+8(q&1)+4(m>>1)+2(m&1) = 32c+8q+2m. Verified identity.
// XOR-quad swizzle + 36-dw row stride: ~2-way banks, b128-aligned,
// loop-invariant addresses. Pad rows (48..63) pre-zeroed once.
// PLUS: grid 512 = 2 waves/SIMD (blocks b, b+256 duplicate one tile; only
// b<256 writes) — second resident wave fills the serial chain's stall
// cycles; VALU/MFMA pipes both stay <100% at x2.
// ---------------------------------------------------------------------------
__global__ __launch_bounds__(256) void admm_mfma(
    const float* __restrict__ raw,
    const ushort* __restrict__ Th, const ushort* __restrict__ Tl,
    const ushort* __restrict__ T0h, const ushort* __restrict__ T0l,
    const float* __restrict__ blp, const float* __restrict__ bup,
    float* __restrict__ outp) {
  __shared__ __align__(16) float UL[4][1152];   // per wave: hi 576 dw | lo 576 dw
  const int tid = threadIdx.x, wave = tid >> 6, lane = tid & 63;
  const int l15 = lane & 15, q = lane >> 4;
  const int bid = blockIdx.x;
  const bool dowrite = bid < 256;
  const long rowbase = (long)(bid & 255) * 64 + wave * 16;

  float* ubase = UL[wave];
  // pre-zero own region (covers pad rows; no barrier needed, DS in-order)
  for (int i = lane; i < 1152; i += 64) ubase[i] = 0.0f;

  const int l7 = l15 & 7;
  uint* uw = (uint*)ubase;
  uint* wp0 = uw + 36 * l15 + (((0 + (q >> 1)) ^ l7) << 2) + 2 * (q & 1);
  uint* wp1 = uw + 36 * l15 + (((2 + (q >> 1)) ^ l7) << 2) + 2 * (q & 1);
  uint* wp2 = uw + 36 * l15 + (((4 + (q >> 1)) ^ l7) << 2) + 2 * (q & 1);
  const float* rp0 = ubase + 36 * l15 + ((q ^ l7) << 2);
  const float* rp1 = ubase + 36 * l15 + (((4 + q) ^ l7) << 2);

  // bounds for n = 16t + 4q + r
  f32x4 bl[3], bu[3];
#pragma unroll
  for (int t = 0; t < 3; ++t) {
    bl[t] = *(const f32x4*)(blp + 16 * t + 4 * q);
    bu[t] = *(const f32x4*)(bup + 16 * t + 4 * q);
  }

  // ---- peel: base = W_1 = T0 * q^T (16x16x32, A=T0-frag, B=raw-frag) -----
  f32x4 W[3], base[3];
  {
    bf16x8 t0h[3], t0l[3];
#pragma unroll
    for (int t = 0; t < 3; ++t) {
      t0h[t] = *(const bf16x8*)(T0h + (16 * t + l15) * 32 + q * 8);
      t0l[t] = *(const bf16x8*)(T0l + (16 * t + l15) * 32 + q * 8);
    }
    float qa[8];
    if (q < 3) {
      const float* rp = raw + (rowbase + l15) * 24 + q * 8;
      float4 v0 = *(const float4*)rp;
      float4 v1 = *(const float4*)(rp + 4);
      qa[0] = v0.x; qa[1] = v0.y; qa[2] = v0.z; qa[3] = v0.w;
      qa[4] = v1.x; qa[5] = v1.y; qa[6] = v1.z; qa[7] = v1.w;
    } else {
#pragma unroll
      for (int j = 0; j < 8; ++j) qa[j] = 0.0f;
    }
    bf16x8 qhi, qlo;
    splitPack(qa, qhi, qlo);
#pragma unroll
    for (int t = 0; t < 3; ++t) {
      f32x4 acc = {0.0f, 0.0f, 0.0f, 0.0f};
      acc = __builtin_amdgcn_mfma_f32_16x16x32_bf16(t0h[t], qhi, acc, 0, 0, 0);
      acc = __builtin_amdgcn_mfma_f32_16x16x32_bf16(t0h[t], qlo, acc, 0, 0, 0);
      acc = __builtin_amdgcn_mfma_f32_16x16x32_bf16(t0l[t], qhi, acc, 0, 0, 0);
      base[t] = acc; W[t] = acc;
    }
  }

  // ---- T A-fragments (16x16x32): th[t][c] = T[16t+l15][32c+8q+j] ----------
  bf16x8 th[3][2], tl[3][2];
#pragma unroll
  for (int t = 0; t < 3; ++t)
#pragma unroll
    for (int c = 0; c < 2; ++c) {
      th[t][c] = *(const bf16x8*)(Th + (16 * t + l15) * 64 + 32 * c + q * 8);
      tl[t][c] = *(const bf16x8*)(Tl + (16 * t + l15) * 64 + 32 * c + q * 8);
    }

  // clip W[t] -> u (f32x4) and C = base + (W-Z); pack+store u to LDS
#define PACKST(t, WPT, CC)                                           \
  {                                                                  \
    f32x4 u_;                                                        \
    _Pragma("unroll") for (int r = 0; r < 4; ++r) {                  \
      float w_ = W[t][r];                                            \
      float z_ = fminf(fmaxf(w_, bl[t][r]), bu[t][r]);               \
      float yy_ = w_ - z_;                                           \
      u_[r] = z_ - yy_;                                              \
      CC[r] = base[t][r] + yy_;                                      \
    }                                                                \
    uint h0_, h1_, l0_, l1_;                                         \
    packPairs(u_, h0_, h1_, l0_, l1_);                               \
    WPT[0] = h0_; WPT[1] = h1_; WPT[576] = l0_; WPT[577] = l1_;      \
  }

#pragma unroll 1
  for (int it = 2; it < ADMM_ITERS; ++it) {   // 98 updates: W_1 -> W_99
    f32x4 C0, C1, C2;
    PACKST(0, wp0, C0);
    PACKST(1, wp1, C1);
    PACKST(2, wp2, C2);
    bf16x8 uh0 = *(const bf16x8*)rp0;
    bf16x8 uh1 = *(const bf16x8*)rp1;
    bf16x8 ul0 = *(const bf16x8*)(rp0 + 576);
    bf16x8 ul1 = *(const bf16x8*)(rp1 + 576);
    f32x4 a0 = C0, a1 = C1, a2 = C2;
    a0 = __builtin_amdgcn_mfma_f32_16x16x32_bf16(th[0][0], uh0, a0, 0, 0, 0);
    a1 = __builtin_amdgcn_mfma_f32_16x16x32_bf16(th[1][0], uh0, a1, 0, 0, 0);
    a2 = __builtin_amdgcn_mfma_f32_16x16x32_bf16(th[2][0], uh0, a2, 0, 0, 0);
    a0 = __builtin_amdgcn_mfma_f32_16x16x32_bf16(th[0][1], uh1, a0, 0, 0, 0);
    a1 = __builtin_amdgcn_mfma_f32_16x16x32_bf16(th[1][1], uh1, a1, 0, 0, 0);
    a2 = __builtin_amdgcn_mfma_f32_16x16x32_bf16(th[2][1], uh1, a2, 0, 0, 0);
    a0 = __builtin_amdgcn_mfma_f32_16x16x32_bf16(th[0][0], ul0, a0, 0, 0, 0);
    a1 = __builtin_amdgcn_mfma_f32_16x16x32_bf16(th[1][0], ul0, a1, 0, 0, 0);
    a2 = __builtin_amdgcn_mfma_f32_16x16x32_bf16(th[2][0], ul0, a2, 0, 0, 0);
    a0 = __builtin_amdgcn_mfma_f32_16x16x32_bf16(th[0][1], ul1, a0, 0, 0, 0);
    a1 = __builtin_amdgcn_mfma_f32_16x16x32_bf16(th[1][1], ul1, a1, 0, 0, 0);
    a2 = __builtin_amdgcn_mfma_f32_16x16x32_bf16(th[2][1], ul1, a2, 0, 0, 0);
    a0 = __builtin_amdgcn_mfma_f32_16x16x32_bf16(tl[0][0], uh0, a0, 0, 0, 0);
    a1 = __builtin_amdgcn_mfma_f32_16x16x32_bf16(tl[1][0], uh0, a1, 0, 0, 0);
    a2 = __builtin_amdgcn_mfma_f32_16x16x32_bf16(tl[2][0], uh0, a2, 0, 0, 0);
    a0 = __builtin_amdgcn_mfma_f32_16x16x32_bf16(tl[0][1], uh1, a0, 0, 0, 0);
    a1 = __builtin_amdgcn_mfma_f32_16x16x32_bf16(tl[1][1], uh1, a1, 0, 0, 0);
    a2 = __builtin_amdgcn_mfma_f32_16x16x32_bf16(tl[2][1], uh1, a2, 0, 0, 0);
    W[0] = a0; W[1] = a1; W[2] = a2;
  }

  // ---- epilogue: X_100 = base + T*u_99 (yy cancels); tiles 0,1 only -------
  {
    f32x4 C0, C1, C2;
    PACKST(0, wp0, C0);
    PACKST(1, wp1, C1);
    PACKST(2, wp2, C2);
    bf16x8 uh0 = *(const bf16x8*)rp0;
    bf16x8 uh1 = *(const bf16x8*)rp1;
    bf16x8 ul0 = *(const bf16x8*)(rp0 + 576);
    bf16x8 ul1 = *(const bf16x8*)(rp1 + 576);
    f32x4 x0 = base[0], x1 = base[1];
    x0 = __builtin_amdgcn_mfma_f32_16x16x32_bf16(th[0][0], uh0, x0, 0, 0, 0);
    x1 = __builtin_amdgcn_mfma_f32_16x16x32_bf16(th[1][0], uh0, x1, 0, 0, 0);
    x0 = __builtin_amdgcn_mfma_f32_16x16x32_bf16(th[0][1], uh1, x0, 0, 0, 0);
    x1 = __builtin_amdgcn_mfma_f32_16x16x32_bf16(th[1][1], uh1, x1, 0, 0, 0);
    x0 = __builtin_amdgcn_mfma_f32_16x16x32_bf16(th[0][0], ul0, x0, 0, 0, 0);
    x1 = __builtin_amdgcn_mfma_f32_16x16x32_bf16(th[1][0], ul0, x1, 0, 0, 0);
    x0 = __builtin_amdgcn_mfma_f32_16x16x32_bf16(th[0][1], ul1, x0, 0, 0, 0);
    x1 = __builtin_amdgcn_mfma_f32_16x16x32_bf16(th[1][1], ul1, x1, 0, 0, 0);
    x0 = __builtin_amdgcn_mfma_f32_16x16x32_bf16(tl[0][0], uh0, x0, 0, 0, 0);
    x1 = __builtin_amdgcn_mfma_f32_16x16x32_bf16(tl[1][0], uh0, x1, 0, 0, 0);
    x0 = __builtin_amdgcn_mfma_f32_16x16x32_bf16(tl[0][1], uh1, x0, 0, 0, 0);
    x1 = __builtin_amdgcn_mfma_f32_16x16x32_bf16(tl[1][1], uh1, x1, 0, 0, 0);
    if (dowrite) {
      *(f32x4*)(outp + (rowbase + l15) * 24 + 4 * q) = x0;
      if (q < 2) *(f32x4*)(outp + (rowbase + l15) * 24 + 16 + 4 * q) = x1;
    }
  }
#undef PACKST
}

// ---------------------------------------------------------------------------
extern "C" void kernel_launch(void* const* d_in, const int* in_sizes, int n_in,
                              void* d_out, int out_size, void* d_ws, size_t ws_size,
                              hipStream_t stream) {
  const float* state = (const float*)d_in[0];
  const float* Aeq   = (const float*)d_in[1];
  const float* beq   = (const float*)d_in[2];
  const float* Ain   = (const float*)d_in[3];
  const float* bin   = (const float*)d_in[4];
  const float* ub    = (const float*)d_in[5];
  const float* lb    = (const float*)d_in[6];
  const float* W1    = (const float*)d_in[7];
  const float* b1    = (const float*)d_in[8];
  const float* W2    = (const float*)d_in[9];
  const float* b2    = (const float*)d_in[10];
  const float* W3    = (const float*)d_in[11];
  const float* b3    = (const float*)d_in[12];

  const int Bn = in_sizes[0] / 512;            // 16384
  char* ws = (char*)d_ws;
  ushort* stateB = (ushort*)(ws + 0);          // 16384x512 bf16  (16 MB)
  ushort* W1T    = (ushort*)(ws + 16777216);   // 1024x512        (1 MB)
  ushort* W2T    = (ushort*)(ws + 17825792);   // 1024x1024       (2 MB)
  ushort* W3T    = (ushort*)(ws + 19922944);   // 32x1024 (rows>=24 zero)
  ushort* Th     = (ushort*)(ws + 19993600);   // 48x64 bf16 hi
  ushort* Tl     = (ushort*)(ws + 19999744);   // 48x64 bf16 lo
  ushort* T0h    = (ushort*)(ws + 20005888);   // 48x32 bf16 hi
  ushort* T0l    = (ushort*)(ws + 20008960);   // 48x32 bf16 lo
  float*  blp    = (float*) (ws + 20012032);   // 48
  float*  bup    = (float*) (ws + 20012224);   // 48
  ushort* H1     = (ushort*)(ws + 21565440);   // 16384x1024 bf16 (32 MB)
  ushort* H2     = (ushort*)(ws + 55119872);   // 16384x1024 bf16 (32 MB)
  float*  rawb   = (float*)d_out;              // gemm3 out = admm in (in-place)

  const int n4 = (Bn * 512) / 4;
  const int nConv = n4 / 256;                  // 8192
  const int nPrep = nConv + 512 + 1024 + 32 + 1;
  prep_all<<<nPrep, 256, 0, stream>>>(state, stateB, n4, W1, W1T, W2, W2T, W3, W3T,
                                      Aeq, beq, Ain, bin, ub, lb,
                                      Th, Tl, T0h, T0l, blp, bup);

  const int nblkN = 1024 / 256;                // 4
  const int nwg = (Bn / 256) * nblkN;          // 256 (div by 8 -> swizzle ok)
  gemm8p<<<nwg, 512, 0, stream>>>(stateB, W1T, b1, H1, 512, 1024, nblkN);
  gemm8p<<<nwg, 512, 0, stream>>>(H1, W2T, b2, H2, 1024, 1024, nblkN);
  gemm_bt<64, 32, 4, 1, 1, 2, 1><<<dim3(1, Bn / 64), 256, 0, stream>>>(
      H2, W3T, b3, rawb, 1024, 24, 24);

  // 512 blocks = 2 waves/SIMD (pairs duplicate a tile; only bid<256 writes)
  admm_mfma<<<512, 256, 0, stream>>>(rawb, Th, Tl, T0h, T0l, blp, bup,
                                     (float*)d_out);
}

// Round 6
// 268.369 us; speedup vs baseline: 1.0724x; 1.0724x over previous
//
#include <hip/hip_runtime.h>

using uint = unsigned int;
using ushort = unsigned short;

typedef __attribute__((ext_vector_type(8))) short bf16x8;
typedef __attribute__((ext_vector_type(4))) short bf16x4;
typedef __attribute__((ext_vector_type(4))) float f32x4;

#define ADMM_ITERS 100
#define RHO_C 1.0f
#define SIGMA_C 1e-6f

__device__ inline ushort f2bf(float f) {
  union { float f; uint u; } c; c.f = f;
  uint u = c.u;
  uint r = (u + 0x7fffu + ((u >> 16) & 1u)) >> 16;
  return (ushort)r;
}

__device__ inline void gload_lds16(const void* g, void* l) {
  __builtin_amdgcn_global_load_lds(
      (const __attribute__((address_space(1))) void*)g,
      (__attribute__((address_space(3))) void*)l, 16, 0, 0);
}

// Split 8 f32 -> hi/lo bf16x8 by TRUNCATION (hi = mantissa-masked; lo = exact
// residual, truncated). Residual error ~2^-16 relative.
__device__ inline void splitPack(const float* x, bf16x8& hi, bf16x8& lo) {
#pragma unroll
  for (int j = 0; j < 8; ++j) {
    uint b = __float_as_uint(x[j]);
    uint hb = b & 0xffff0000u;
    float lf = x[j] - __uint_as_float(hb);
    hi[j] = (short)(b >> 16);
    lo[j] = (short)(__float_as_uint(lf) >> 16);
  }
}

// 4 f32 -> two hi-pair dwords + two lo-pair dwords (truncation split, even
// element in low 16 bits). Bit-identical values to splitPack.
__device__ inline void packPairs(const f32x4& x, uint& h0, uint& h1,
                                 uint& l0, uint& l1) {
  uint b0 = __float_as_uint(x[0]), b1 = __float_as_uint(x[1]);
  uint b2 = __float_as_uint(x[2]), b3 = __float_as_uint(x[3]);
  float r0 = x[0] - __uint_as_float(b0 & 0xffff0000u);
  float r1 = x[1] - __uint_as_float(b1 & 0xffff0000u);
  float r2 = x[2] - __uint_as_float(b2 & 0xffff0000u);
  float r3 = x[3] - __uint_as_float(b3 & 0xffff0000u);
  h0 = __builtin_amdgcn_perm(b1, b0, 0x07060302u);
  h1 = __builtin_amdgcn_perm(b3, b2, 0x07060302u);
  l0 = __builtin_amdgcn_perm(__float_as_uint(r1), __float_as_uint(r0), 0x07060302u);
  l1 = __builtin_amdgcn_perm(__float_as_uint(r3), __float_as_uint(r2), 0x07060302u);
}

// ---------------------------------------------------------------------------
// prep bodies (fused into prep_all)
// ---------------------------------------------------------------------------
__device__ void transpose_body(const float* __restrict__ in, ushort* __restrict__ out,
                               int R, int C, int Cout, int bx, int by, int tid) {
  __shared__ float t[32][33];
  const int c0 = bx * 32, r0 = by * 32;
  const int tx = tid & 31, ty = tid >> 5;
  for (int rr = ty; rr < 32; rr += 8) {
    int r = r0 + rr, c = c0 + tx;
    float v = 0.0f;
    if (r < R && c < C) v = in[(long)r * C + c];
    t[rr][tx] = v;
  }
  __syncthreads();
  for (int rr = ty; rr < 32; rr += 8) {
    int c = c0 + rr, r = r0 + tx;
    if (c < Cout && r < R) out[(long)c * R + r] = f2bf(t[tx][rr]);
  }
}

// ADMM setup -> MFMA operand form. (unchanged; see earlier rounds)
__device__ void setup_body(const float* __restrict__ Aeq, const float* __restrict__ beq,
                           const float* __restrict__ A, const float* __restrict__ b,
                           const float* __restrict__ ub, const float* __restrict__ lb,
                           ushort* __restrict__ Th, ushort* __restrict__ Tl,
                           ushort* __restrict__ T0h, ushort* __restrict__ T0l,
                           float* __restrict__ blp, float* __restrict__ bup, int t) {
  __shared__ float Aug[24][48];
  __shared__ float A12[12 * 24];
  __shared__ float fac[24];
  __shared__ float Tx[24][36];
  for (int i = t; i < 48 * 64; i += 256) { Th[i] = 0; Tl[i] = 0; }
  for (int i = t; i < 48 * 32; i += 256) { T0h[i] = 0; T0l[i] = 0; }
  if (t < 96)  A12[t] = Aeq[t];
  if (t < 192) A12[96 + t] = A[t];
  __syncthreads();
  for (int idx = t; idx < 576; idx += 256) {
    int j = idx / 24, k = idx % 24;
    float s = (j == k) ? (1.0f + SIGMA_C + 2.0f * RHO_C) : 0.0f;
    for (int r = 0; r < 12; ++r) s += RHO_C * A12[r * 24 + j] * A12[r * 24 + k];
    Aug[j][k] = s;
    Aug[j][24 + k] = (j == k) ? 1.0f : 0.0f;
  }
  __syncthreads();
  for (int p = 0; p < 24; ++p) {
    float rp = 1.0f / Aug[p][p];
    if (t < 24) fac[t] = Aug[t][p];
    __syncthreads();
    if (t < 48) Aug[p][t] *= rp;
    __syncthreads();
    for (int idx = t; idx < 24 * 48; idx += 256) {
      int r = idx / 48, c = idx % 48;
      if (r != p) Aug[r][c] -= fac[r] * Aug[p][c];
    }
    __syncthreads();
  }
  auto splitStore = [](ushort* hp, ushort* lp, int i, float v) {
    ushort hs = f2bf(v);
    float hf = __uint_as_float(((uint)hs) << 16);
    ushort ls = f2bf(v - hf);
    hp[i] = hs; lp[i] = ls;
  };
  for (int idx = t; idx < 24 * 36; idx += 256) {
    int n = idx / 36, k = idx % 36;
    float v;
    if (k < 24) v = 2.0f * Aug[n][24 + k];
    else {
      v = 0.0f;
      for (int j = 0; j < 24; ++j) v += Aug[n][24 + j] * A12[(k - 24) * 24 + j];
    }
    Tx[n][k] = v;
    splitStore(Th, Tl, n * 64 + k, v);
  }
  __syncthreads();
  for (int idx = t; idx < 12 * 36; idx += 256) {
    int m = idx / 36, k = idx % 36;
    float v = 0.0f;
    for (int j = 0; j < 24; ++j) v += A12[m * 24 + j] * Tx[j][k];
    splitStore(Th, Tl, (24 + m) * 64 + k, v);
  }
  for (int idx = t; idx < 36 * 24; idx += 256) {
    int n = idx / 24, k = idx % 24;
    float v;
    if (n < 24) v = Aug[n][24 + k];
    else {
      v = 0.0f;
      for (int j = 0; j < 24; ++j) v += A12[(n - 24) * 24 + j] * Aug[j][24 + k];
    }
    splitStore(T0h, T0l, n * 32 + k, v);
  }
  if (t < 48) {
    float lv, uv;
    if (t < 24)      { lv = lb[t]; uv = ub[t]; }
    else if (t < 28) { lv = beq[t - 24]; uv = lv; }
    else if (t < 36) { lv = -1e30f; uv = b[t - 28]; }
    else             { lv = -1e30f; uv = 1e30f; }
    blp[t] = lv; bup[t] = uv;
  }
}

// Fused prep: [0,nConv) convert | [+512) W1T | [+1024) W2T | [+32) W3T | [1) setup
__global__ void prep_all(
    const float* __restrict__ state, ushort* __restrict__ stateB, int n4,
    const float* __restrict__ W1, ushort* __restrict__ W1T,
    const float* __restrict__ W2, ushort* __restrict__ W2T,
    const float* __restrict__ W3, ushort* __restrict__ W3T,
    const float* __restrict__ Aeq, const float* __restrict__ beq,
    const float* __restrict__ A, const float* __restrict__ b,
    const float* __restrict__ ub, const float* __restrict__ lb,
    ushort* __restrict__ Th, ushort* __restrict__ Tl,
    ushort* __restrict__ T0h, ushort* __restrict__ T0l,
    float* __restrict__ blp, float* __restrict__ bup) {
  const int nConv = n4 >> 8;
  int bb = blockIdx.x;
  if (bb < nConv) {
    int i = bb * 256 + threadIdx.x;
    if (i < n4) {
      float4 v = ((const float4*)state)[i];
      uint2 p;
      p.x = (uint)f2bf(v.x) | ((uint)f2bf(v.y) << 16);
      p.y = (uint)f2bf(v.z) | ((uint)f2bf(v.w) << 16);
      ((uint2*)stateB)[i] = p;
    }
    return;
  }
  bb -= nConv;
  if (bb < 512)  { transpose_body(W1, W1T, 512, 1024, 1024, bb & 31, bb >> 5, threadIdx.x); return; }
  bb -= 512;
  if (bb < 1024) { transpose_body(W2, W2T, 1024, 1024, 1024, bb & 31, bb >> 5, threadIdx.x); return; }
  bb -= 1024;
  if (bb < 32)   { transpose_body(W3, W3T, 1024, 24, 32, 0, bb, threadIdx.x); return; }
  setup_body(Aeq, beq, A, b, ub, lb, Th, Tl, T0h, T0l, blp, bup, threadIdx.x);
}

// ---------------------------------------------------------------------------
// bf16 GEMM, C = A[M,K] * Bt[N,K]^T — m97-style staging (skinny final layer).
// ---------------------------------------------------------------------------
template<int BM, int BN, int WM, int WN, int TM, int TN, int MODE>
__global__ __launch_bounds__(256) void gemm_bt(
    const ushort* __restrict__ A, const ushort* __restrict__ Bt,
    const float* __restrict__ bias, void* __restrict__ Cout_,
    int K, int ldc, int nvalid) {
  __shared__ char lds[(BM + BN) * 64];
  char* ldsA = lds;
  char* ldsB = lds + BM * 64;

  const int tid = threadIdx.x;
  const int wave = tid >> 6;
  const int lane = tid & 63;
  const int blockM = blockIdx.y * BM;
  const int blockN = blockIdx.x * BN;
  const int wm = (wave / WN) * (TM * 16);
  const int wn = (wave % WN) * (TN * 16);

  f32x4 acc[TM][TN] = {};

  const int l15 = lane & 15;
  const int kq = lane >> 4;
  constexpr int AI = BM / 16;
  constexpr int TOT = (BM + BN) / 16;
  const int srow = lane >> 2;
  const int kb = (lane & 3) ^ ((srow >> 1) & 3);

  for (int k0 = 0; k0 < K; k0 += 32) {
    for (int inst = wave; inst < TOT; inst += 4) {
      const bool isA = inst < AI;
      const int i = isA ? inst : inst - AI;
      const ushort* gp = (isA ? A : Bt)
          + (long)((isA ? blockM : blockN) + i * 16 + srow) * K + (k0 + kb * 8);
      char* lp = (isA ? ldsA : ldsB) + i * 1024;
      gload_lds16(gp, lp);
    }
    __syncthreads();

    bf16x8 af[TM], bfr[TN];
#pragma unroll
    for (int i = 0; i < TM; ++i) {
      int r = wm + i * 16 + l15;
      int ch = kq ^ ((r >> 1) & 3);
      af[i] = *(const bf16x8*)(ldsA + r * 64 + ch * 16);
    }
#pragma unroll
    for (int j = 0; j < TN; ++j) {
      int r = wn + j * 16 + l15;
      int ch = kq ^ ((r >> 1) & 3);
      bfr[j] = *(const bf16x8*)(ldsB + r * 64 + ch * 16);
    }
#pragma unroll
    for (int i = 0; i < TM; ++i)
#pragma unroll
      for (int j = 0; j < TN; ++j)
        acc[i][j] = __builtin_amdgcn_mfma_f32_16x16x32_bf16(af[i], bfr[j], acc[i][j], 0, 0, 0);
    __syncthreads();
  }

  const int ro = lane >> 4;
#pragma unroll
  for (int i = 0; i < TM; ++i) {
#pragma unroll
    for (int j = 0; j < TN; ++j) {
      const int col = blockN + wn + j * 16 + l15;
      float bv;
      if (MODE == 0) bv = bias[col];
      else bv = (col < nvalid) ? bias[col] : 0.0f;
#pragma unroll
      for (int r = 0; r < 4; ++r) {
        const int row = blockM + wm + i * 16 + ro * 4 + r;
        float v = acc[i][j][r] + bv;
        if (MODE == 0) {
          v = fmaxf(v, 0.0f);
          ((ushort*)Cout_)[(long)row * ldc + col] = f2bf(v);
        } else {
          if (col < nvalid) ((float*)Cout_)[(long)row * ldc + col] = v;
        }
      }
    }
  }
}

// ---------------------------------------------------------------------------
// 256x256 8-phase bf16 GEMM (T1+T2+T3+T4+T5) — unchanged.
// ---------------------------------------------------------------------------
#define GEMM8P_QUAD(MI0, NJ0)                                                 \
  _Pragma("unroll") for (int mi_ = 0; mi_ < 4; ++mi_)                         \
  _Pragma("unroll") for (int nj_ = 0; nj_ < 2; ++nj_)                         \
  _Pragma("unroll") for (int kk_ = 0; kk_ < 2; ++kk_)                         \
    acc[(MI0) + mi_][(NJ0) + nj_] = __builtin_amdgcn_mfma_f32_16x16x32_bf16(  \
        aF[mi_][kk_], bF[(NJ0) + nj_][kk_], acc[(MI0) + mi_][(NJ0) + nj_],    \
        0, 0, 0);

#define GEMM8P_SYNC_PRE()                              \
  __builtin_amdgcn_s_barrier();                        \
  asm volatile("s_waitcnt lgkmcnt(0)" ::: "memory");   \
  __builtin_amdgcn_sched_barrier(0);                   \
  __builtin_amdgcn_s_setprio(1);

#define GEMM8P_SYNC_POST()                             \
  __builtin_amdgcn_s_setprio(0);                       \
  __builtin_amdgcn_s_barrier();

__global__ __launch_bounds__(512, 2) void gemm8p(
    const ushort* __restrict__ A, const ushort* __restrict__ Bt,
    const float* __restrict__ bias, ushort* __restrict__ Cout,
    int K, int ldc, int nblk_n) {
  __shared__ __align__(16) char ldsc[131072];   // [2 buf][A 32K | B 32K]

  const int nwg = gridDim.x;
  const int bid = blockIdx.x;
  const int swz = (bid & 7) * (nwg >> 3) + (bid >> 3);
  const int blockM = (swz / nblk_n) * 256;
  const int blockN = (swz % nblk_n) * 256;

  const int tid = threadIdx.x;
  const int wave = tid >> 6;
  const int lane = tid & 63;
  const int l15 = lane & 15;
  const int q = lane >> 4;
  const int wm = (wave >> 2) * 128;
  const int wn = (wave & 3) * 64;
  const int nt = K >> 6;

  f32x4 acc[8][4] = {};

  auto stage = [&](int ts, int h) {
    if (ts >= nt) return;
    char* base = ldsc + ((ts & 1) << 16) + (h << 14);
#pragma unroll
    for (int j = 0; j < 2; ++j) {
      const int idx = wave * 64 + j * 512 + lane;
      const int row = idx >> 3;
      const int cs = (idx & 7) ^ (row & 7);
      const ushort* gp =
          (h < 2 ? A + (long)(blockM + ((h & 1) << 7) + row) * K
                 : Bt + (long)(blockN + ((h & 1) << 7) + row) * K)
          + (ts << 6) + cs * 8;
      gload_lds16(gp, base + ((wave * 64 + j * 512) << 4));
    }
  };
  auto dsA = [&](int cb, int mi, int kk) {
    const int r = wm + mi * 16 + l15;
    const int cs = (kk * 4 + q) ^ (r & 7);
    return *(const bf16x8*)(ldsc + (cb << 16) + r * 128 + cs * 16);
  };
  auto dsB = [&](int cb, int nj, int kk) {
    const int r = wn + nj * 16 + l15;
    const int cs = (kk * 4 + q) ^ (r & 7);
    return *(const bf16x8*)(ldsc + (cb << 16) + 32768 + r * 128 + cs * 16);
  };

  stage(0, 0); stage(0, 1); stage(0, 2); stage(0, 3);
  stage(1, 0);
  asm volatile("s_waitcnt vmcnt(2)" ::: "memory");
  __builtin_amdgcn_s_barrier();

  bf16x8 aF[4][2], bF[4][2];
#pragma unroll 1
  for (int t = 0; t < nt; ++t) {
    const int cb = t & 1;
#pragma unroll
    for (int mi = 0; mi < 4; ++mi)
#pragma unroll
      for (int kk = 0; kk < 2; ++kk) aF[mi][kk] = dsA(cb, mi, kk);
#pragma unroll
    for (int nj = 0; nj < 2; ++nj)
#pragma unroll
      for (int kk = 0; kk < 2; ++kk) bF[nj][kk] = dsB(cb, nj, kk);
    stage(t + 1, 1);
    GEMM8P_SYNC_PRE();
    GEMM8P_QUAD(0, 0);
    GEMM8P_SYNC_POST();
#pragma unroll
    for (int nj = 2; nj < 4; ++nj)
#pragma unroll
      for (int kk = 0; kk < 2; ++kk) bF[nj][kk] = dsB(cb, nj, kk);
    stage(t + 1, 2);
    GEMM8P_SYNC_PRE();
    GEMM8P_QUAD(0, 2);
    GEMM8P_SYNC_POST();
#pragma unroll
    for (int mi = 0; mi < 4; ++mi)
#pragma unroll
      for (int kk = 0; kk < 2; ++kk) aF[mi][kk] = dsA(cb, 4 + mi, kk);
    stage(t + 1, 3);
    GEMM8P_SYNC_PRE();
    GEMM8P_QUAD(4, 2);
    GEMM8P_SYNC_POST();
    stage(t + 2, 0);
    if (t + 2 < nt) { asm volatile("s_waitcnt vmcnt(2)" ::: "memory"); }
    else            { asm volatile("s_waitcnt vmcnt(0)" ::: "memory"); }
    __builtin_amdgcn_s_barrier();
    __builtin_amdgcn_s_setprio(1);
    GEMM8P_QUAD(4, 0);
    GEMM8P_SYNC_POST();
  }

#pragma unroll
  for (int mi = 0; mi < 8; ++mi) {
#pragma unroll
    for (int nj = 0; nj < 4; ++nj) {
      const int col = blockN + wn + nj * 16 + l15;
      const float bv = bias[col];
#pragma unroll
      for (int r = 0; r < 4; ++r) {
        const int row = blockM + wm + mi * 16 + q * 4 + r;
        float v = acc[mi][nj][r] + bv;
        v = fmaxf(v, 0.0f);
        Cout[(long)row * ldc + col] = f2bf(v);
      }
    }
  }
}

// ---------------------------------------------------------------------------
// ADMM via MFMA (round-6: r5 structure with CORRECT bank-balanced LDS layout).
// r5 post-mortem: 40.5M bank-conflict cycles — XOR-ing a quad index into an
// ADDITIVE row offset clusters banks instead of spreading them. Fix: plain
// layout H[l15][P] with row stride S=36 dwords; bank = (4*l15 + P) mod 32.
// Verified census: b64 writes (P=8t+2q) -> exactly 4 dwords/bank (floor);
// b128 reads (P=16c+4q) -> exactly 8 dwords/bank (floor). No XOR anywhere.
// Pair identity: dword m of chunk-c read = pair P=16c+4q+m = elements
// n=32c+8q+2m{,+1} = B-fragment k=32c+8q+j with even element in low half
// (packPairs order). Pad pairs P=24..31 pre-zeroed. hi at [0,576), lo +576.
// Keeps: pack-before-store (6 b64 wr + 4 b128 rd/iter, no barriers — DS is
// in-order per wave), 18 K32 MFMAs in 3 round-robined 6-deep chains,
// epilogue X_100 = base + T*u_99, and grid 512 = 2 waves/SIMD duplication
// (blocks b, b+256 compute the same tile; only b<256 writes).
// ---------------------------------------------------------------------------
__global__ __launch_bounds__(256) void admm_mfma(
    const float* __restrict__ raw,
    const ushort* __restrict__ Th, const ushort* __restrict__ Tl,
    const ushort* __restrict__ T0h, const ushort* __restrict__ T0l,
    const float* __restrict__ blp, const float* __restrict__ bup,
    float* __restrict__ outp) {
  __shared__ __align__(16) float UL[4][1152];   // per wave: hi 576 dw | lo 576 dw
  const int tid = threadIdx.x, wave = tid >> 6, lane = tid & 63;
  const int l15 = lane & 15, q = lane >> 4;
  const int bid = blockIdx.x;
  const bool dowrite = bid < 256;
  const long rowbase = (long)(bid & 255) * 64 + wave * 16;

  float* ubase = UL[wave];
  // pre-zero own region (covers pad pairs P=24..31; DS in-order per wave)
  for (int i = lane; i < 1152; i += 64) ubase[i] = 0.0f;

  uint* uw = (uint*)ubase;
  uint* wpB = uw + 36 * l15 + 2 * q;            // write base: +8t (+576 lo)
  const float* rpB = ubase + 36 * l15 + 4 * q;  // read base: +16c (+576 lo)

  // bounds for n = 16t + 4q + r
  f32x4 bl[3], bu[3];
#pragma unroll
  for (int t = 0; t < 3; ++t) {
    bl[t] = *(const f32x4*)(blp + 16 * t + 4 * q);
    bu[t] = *(const f32x4*)(bup + 16 * t + 4 * q);
  }

  // ---- peel: base = W_1 = T0 * q^T (16x16x32, A=T0-frag, B=raw-frag) -----
  f32x4 W[3], base[3];
  {
    bf16x8 t0h[3], t0l[3];
#pragma unroll
    for (int t = 0; t < 3; ++t) {
      t0h[t] = *(const bf16x8*)(T0h + (16 * t + l15) * 32 + q * 8);
      t0l[t] = *(const bf16x8*)(T0l + (16 * t + l15) * 32 + q * 8);
    }
    float qa[8];
    if (q < 3) {
      const float* rp = raw + (rowbase + l15) * 24 + q * 8;
      float4 v0 = *(const float4*)rp;
      float4 v1 = *(const float4*)(rp + 4);
      qa[0] = v0.x; qa[1] = v0.y; qa[2] = v0.z; qa[3] = v0.w;
      qa[4] = v1.x; qa[5] = v1.y; qa[6] = v1.z; qa[7] = v1.w;
    } else {
#pragma unroll
      for (int j = 0; j < 8; ++j) qa[j] = 0.0f;
    }
    bf16x8 qhi, qlo;
    splitPack(qa, qhi, qlo);
#pragma unroll
    for (int t = 0; t < 3; ++t) {
      f32x4 acc = {0.0f, 0.0f, 0.0f, 0.0f};
      acc = __builtin_amdgcn_mfma_f32_16x16x32_bf16(t0h[t], qhi, acc, 0, 0, 0);
      acc = __builtin_amdgcn_mfma_f32_16x16x32_bf16(t0h[t], qlo, acc, 0, 0, 0);
      acc = __builtin_amdgcn_mfma_f32_16x16x32_bf16(t0l[t], qhi, acc, 0, 0, 0);
      base[t] = acc; W[t] = acc;
    }
  }

  // ---- T A-fragments (16x16x32): th[t][c] = T[16t+l15][32c+8q+j] ----------
  bf16x8 th[3][2], tl[3][2];
#pragma unroll
  for (int t = 0; t < 3; ++t)
#pragma unroll
    for (int c = 0; c < 2; ++c) {
      th[t][c] = *(const bf16x8*)(Th + (16 * t + l15) * 64 + 32 * c + q * 8);
      tl[t][c] = *(const bf16x8*)(Tl + (16 * t + l15) * 64 + 32 * c + q * 8);
    }

  // clip W[t] -> u, C = base + (W-Z); pack u -> bf16 pairs; store to LDS
#define PACKST(t, CC)                                                \
  {                                                                  \
    f32x4 u_;                                                        \
    _Pragma("unroll") for (int r = 0; r < 4; ++r) {                  \
      float w_ = W[t][r];                                            \
      float z_ = fminf(fmaxf(w_, bl[t][r]), bu[t][r]);               \
      float yy_ = w_ - z_;                                           \
      u_[r] = z_ - yy_;                                              \
      CC[r] = base[t][r] + yy_;                                      \
    }                                                                \
    uint h0_, h1_, l0_, l1_;                                         \
    packPairs(u_, h0_, h1_, l0_, l1_);                               \
    wpB[8 * t] = h0_; wpB[8 * t + 1] = h1_;                          \
    wpB[576 + 8 * t] = l0_; wpB[577 + 8 * t] = l1_;                  \
  }

#pragma unroll 1
  for (int it = 2; it < ADMM_ITERS; ++it) {   // 98 updates: W_1 -> W_99
    f32x4 C0, C1, C2;
    PACKST(0, C0);
    PACKST(1, C1);
    PACKST(2, C2);
    bf16x8 uh0 = *(const bf16x8*)rpB;
    bf16x8 uh1 = *(const bf16x8*)(rpB + 16);
    bf16x8 ul0 = *(const bf16x8*)(rpB + 576);
    bf16x8 ul1 = *(const bf16x8*)(rpB + 592);
    f32x4 a0 = C0, a1 = C1, a2 = C2;
    a0 = __builtin_amdgcn_mfma_f32_16x16x32_bf16(th[0][0], uh0, a0, 0, 0, 0);
    a1 = __builtin_amdgcn_mfma_f32_16x16x32_bf16(th[1][0], uh0, a1, 0, 0, 0);
    a2 = __builtin_amdgcn_mfma_f32_16x16x32_bf16(th[2][0], uh0, a2, 0, 0, 0);
    a0 = __builtin_amdgcn_mfma_f32_16x16x32_bf16(th[0][1], uh1, a0, 0, 0, 0);
    a1 = __builtin_amdgcn_mfma_f32_16x16x32_bf16(th[1][1], uh1, a1, 0, 0, 0);
    a2 = __builtin_amdgcn_mfma_f32_16x16x32_bf16(th[2][1], uh1, a2, 0, 0, 0);
    a0 = __builtin_amdgcn_mfma_f32_16x16x32_bf16(th[0][0], ul0, a0, 0, 0, 0);
    a1 = __builtin_amdgcn_mfma_f32_16x16x32_bf16(th[1][0], ul0, a1, 0, 0, 0);
    a2 = __builtin_amdgcn_mfma_f32_16x16x32_bf16(th[2][0], ul0, a2, 0, 0, 0);
    a0 = __builtin_amdgcn_mfma_f32_16x16x32_bf16(th[0][1], ul1, a0, 0, 0, 0);
    a1 = __builtin_amdgcn_mfma_f32_16x16x32_bf16(th[1][1], ul1, a1, 0, 0, 0);
    a2 = __builtin_amdgcn_mfma_f32_16x16x32_bf16(th[2][1], ul1, a2, 0, 0, 0);
    a0 = __builtin_amdgcn_mfma_f32_16x16x32_bf16(tl[0][0], uh0, a0, 0, 0, 0);
    a1 = __builtin_amdgcn_mfma_f32_16x16x32_bf16(tl[1][0], uh0, a1, 0, 0, 0);
    a2 = __builtin_amdgcn_mfma_f32_16x16x32_bf16(tl[2][0], uh0, a2, 0, 0, 0);
    a0 = __builtin_amdgcn_mfma_f32_16x16x32_bf16(tl[0][1], uh1, a0, 0, 0, 0);
    a1 = __builtin_amdgcn_mfma_f32_16x16x32_bf16(tl[1][1], uh1, a1, 0, 0, 0);
    a2 = __builtin_amdgcn_mfma_f32_16x16x32_bf16(tl[2][1], uh1, a2, 0, 0, 0);
    W[0] = a0; W[1] = a1; W[2] = a2;
  }

  // ---- epilogue: X_100 = base + T*u_99 (yy cancels); tiles 0,1 only -------
  {
    f32x4 C0, C1, C2;
    PACKST(0, C0);
    PACKST(1, C1);
    PACKST(2, C2);
    bf16x8 uh0 = *(const bf16x8*)rpB;
    bf16x8 uh1 = *(const bf16x8*)(rpB + 16);
    bf16x8 ul0 = *(const bf16x8*)(rpB + 576);
    bf16x8 ul1 = *(const bf16x8*)(rpB + 592);
    f32x4 x0 = base[0], x1 = base[1];
    x0 = __builtin_amdgcn_mfma_f32_16x16x32_bf16(th[0][0], uh0, x0, 0, 0, 0);
    x1 = __builtin_amdgcn_mfma_f32_16x16x32_bf16(th[1][0], uh0, x1, 0, 0, 0);
    x0 = __builtin_amdgcn_mfma_f32_16x16x32_bf16(th[0][1], uh1, x0, 0, 0, 0);
    x1 = __builtin_amdgcn_mfma_f32_16x16x32_bf16(th[1][1], uh1, x1, 0, 0, 0);
    x0 = __builtin_amdgcn_mfma_f32_16x16x32_bf16(th[0][0], ul0, x0, 0, 0, 0);
    x1 = __builtin_amdgcn_mfma_f32_16x16x32_bf16(th[1][0], ul0, x1, 0, 0, 0);
    x0 = __builtin_amdgcn_mfma_f32_16x16x32_bf16(th[0][1], ul1, x0, 0, 0, 0);
    x1 = __builtin_amdgcn_mfma_f32_16x16x32_bf16(th[1][1], ul1, x1, 0, 0, 0);
    x0 = __builtin_amdgcn_mfma_f32_16x16x32_bf16(tl[0][0], uh0, x0, 0, 0, 0);
    x1 = __builtin_amdgcn_mfma_f32_16x16x32_bf16(tl[1][0], uh0, x1, 0, 0, 0);
    x0 = __builtin_amdgcn_mfma_f32_16x16x32_bf16(tl[0][1], uh1, x0, 0, 0, 0);
    x1 = __builtin_amdgcn_mfma_f32_16x16x32_bf16(tl[1][1], uh1, x1, 0, 0, 0);
    if (dowrite) {
      *(f32x4*)(outp + (rowbase + l15) * 24 + 4 * q) = x0;
      if (q < 2) *(f32x4*)(outp + (rowbase + l15) * 24 + 16 + 4 * q) = x1;
    }
  }
#undef PACKST
}

// ---------------------------------------------------------------------------
extern "C" void kernel_launch(void* const* d_in, const int* in_sizes, int n_in,
                              void* d_out, int out_size, void* d_ws, size_t ws_size,
                              hipStream_t stream) {
  const float* state = (const float*)d_in[0];
  const float* Aeq   = (const float*)d_in[1];
  const float* beq   = (const float*)d_in[2];
  const float* Ain   = (const float*)d_in[3];
  const float* bin   = (const float*)d_in[4];
  const float* ub    = (const float*)d_in[5];
  const float* lb    = (const float*)d_in[6];
  const float* W1    = (const float*)d_in[7];
  const float* b1    = (const float*)d_in[8];
  const float* W2    = (const float*)d_in[9];
  const float* b2    = (const float*)d_in[10];
  const float* W3    = (const float*)d_in[11];
  const float* b3    = (const float*)d_in[12];

  const int Bn = in_sizes[0] / 512;            // 16384
  char* ws = (char*)d_ws;
  ushort* stateB = (ushort*)(ws + 0);          // 16384x512 bf16  (16 MB)
  ushort* W1T    = (ushort*)(ws + 16777216);   // 1024x512        (1 MB)
  ushort* W2T    = (ushort*)(ws + 17825792);   // 1024x1024       (2 MB)
  ushort* W3T    = (ushort*)(ws + 19922944);   // 32x1024 (rows>=24 zero)
  ushort* Th     = (ushort*)(ws + 19993600);   // 48x64 bf16 hi
  ushort* Tl     = (ushort*)(ws + 19999744);   // 48x64 bf16 lo
  ushort* T0h    = (ushort*)(ws + 20005888);   // 48x32 bf16 hi
  ushort* T0l    = (ushort*)(ws + 20008960);   // 48x32 bf16 lo
  float*  blp    = (float*) (ws + 20012032);   // 48
  float*  bup    = (float*) (ws + 20012224);   // 48
  ushort* H1     = (ushort*)(ws + 21565440);   // 16384x1024 bf16 (32 MB)
  ushort* H2     = (ushort*)(ws + 55119872);   // 16384x1024 bf16 (32 MB)
  float*  rawb   = (float*)d_out;              // gemm3 out = admm in (in-place)

  const int n4 = (Bn * 512) / 4;
  const int nConv = n4 / 256;                  // 8192
  const int nPrep = nConv + 512 + 1024 + 32 + 1;
  prep_all<<<nPrep, 256, 0, stream>>>(state, stateB, n4, W1, W1T, W2, W2T, W3, W3T,
                                      Aeq, beq, Ain, bin, ub, lb,
                                      Th, Tl, T0h, T0l, blp, bup);

  const int nblkN = 1024 / 256;                // 4
  const int nwg = (Bn / 256) * nblkN;          // 256 (div by 8 -> swizzle ok)
  gemm8p<<<nwg, 512, 0, stream>>>(stateB, W1T, b1, H1, 512, 1024, nblkN);
  gemm8p<<<nwg, 512, 0, stream>>>(H1, W2T, b2, H2, 1024, 1024, nblkN);
  gemm_bt<64, 32, 4, 1, 1, 2, 1><<<dim3(1, Bn / 64), 256, 0, stream>>>(
      H2, W3T, b3, rawb, 1024, 24, 24);

  // 512 blocks = 2 waves/SIMD (pairs duplicate a tile; only bid<256 writes)
  admm_mfma<<<512, 256, 0, stream>>>(rawb, Th, Tl, T0h, T0l, blp, bup,
                                     (float*)d_out);
}

// Round 7
// 249.521 us; speedup vs baseline: 1.1534x; 1.0755x over previous
//
#include <hip/hip_runtime.h>

using uint = unsigned int;
using ushort = unsigned short;

typedef __attribute__((ext_vector_type(8))) short bf16x8;
typedef __attribute__((ext_vector_type(4))) short bf16x4;
typedef __attribute__((ext_vector_type(4))) float f32x4;

#define ADMM_ITERS 100
#define RHO_C 1.0f
#define SIGMA_C 1e-6f

__device__ inline ushort f2bf(float f) {
  union { float f; uint u; } c; c.f = f;
  uint u = c.u;
  uint r = (u + 0x7fffu + ((u >> 16) & 1u)) >> 16;
  return (ushort)r;
}

__device__ inline void gload_lds16(const void* g, void* l) {
  __builtin_amdgcn_global_load_lds(
      (const __attribute__((address_space(1))) void*)g,
      (__attribute__((address_space(3))) void*)l, 16, 0, 0);
}

// Split 8 f32 -> hi/lo bf16x8 by TRUNCATION (hi = mantissa-masked; lo = exact
// residual, truncated). Residual error ~2^-16 relative.
__device__ inline void splitPack(const float* x, bf16x8& hi, bf16x8& lo) {
#pragma unroll
  for (int j = 0; j < 8; ++j) {
    uint b = __float_as_uint(x[j]);
    uint hb = b & 0xffff0000u;
    float lf = x[j] - __uint_as_float(hb);
    hi[j] = (short)(b >> 16);
    lo[j] = (short)(__float_as_uint(lf) >> 16);
  }
}

// 4 f32 -> two hi-pair dwords + two lo-pair dwords (truncation split, even
// element in low 16 bits). Bit-identical values to splitPack.
__device__ inline void packPairs(const f32x4& x, uint& h0, uint& h1,
                                 uint& l0, uint& l1) {
  uint b0 = __float_as_uint(x[0]), b1 = __float_as_uint(x[1]);
  uint b2 = __float_as_uint(x[2]), b3 = __float_as_uint(x[3]);
  float r0 = x[0] - __uint_as_float(b0 & 0xffff0000u);
  float r1 = x[1] - __uint_as_float(b1 & 0xffff0000u);
  float r2 = x[2] - __uint_as_float(b2 & 0xffff0000u);
  float r3 = x[3] - __uint_as_float(b3 & 0xffff0000u);
  h0 = __builtin_amdgcn_perm(b1, b0, 0x07060302u);
  h1 = __builtin_amdgcn_perm(b3, b2, 0x07060302u);
  l0 = __builtin_amdgcn_perm(__float_as_uint(r1), __float_as_uint(r0), 0x07060302u);
  l1 = __builtin_amdgcn_perm(__float_as_uint(r3), __float_as_uint(r2), 0x07060302u);
}

// ---------------------------------------------------------------------------
// prep bodies (fused into prep_all)
// ---------------------------------------------------------------------------
__device__ void transpose_body(const float* __restrict__ in, ushort* __restrict__ out,
                               int R, int C, int Cout, int bx, int by, int tid) {
  __shared__ float t[32][33];
  const int c0 = bx * 32, r0 = by * 32;
  const int tx = tid & 31, ty = tid >> 5;
  for (int rr = ty; rr < 32; rr += 8) {
    int r = r0 + rr, c = c0 + tx;
    float v = 0.0f;
    if (r < R && c < C) v = in[(long)r * C + c];
    t[rr][tx] = v;
  }
  __syncthreads();
  for (int rr = ty; rr < 32; rr += 8) {
    int c = c0 + rr, r = r0 + tx;
    if (c < Cout && r < R) out[(long)c * R + r] = f2bf(t[tx][rr]);
  }
}

// ADMM setup -> MFMA operand form. (unchanged; see earlier rounds)
__device__ void setup_body(const float* __restrict__ Aeq, const float* __restrict__ beq,
                           const float* __restrict__ A, const float* __restrict__ b,
                           const float* __restrict__ ub, const float* __restrict__ lb,
                           ushort* __restrict__ Th, ushort* __restrict__ Tl,
                           ushort* __restrict__ T0h, ushort* __restrict__ T0l,
                           float* __restrict__ blp, float* __restrict__ bup, int t) {
  __shared__ float Aug[24][48];
  __shared__ float A12[12 * 24];
  __shared__ float fac[24];
  __shared__ float Tx[24][36];
  for (int i = t; i < 48 * 64; i += 256) { Th[i] = 0; Tl[i] = 0; }
  for (int i = t; i < 48 * 32; i += 256) { T0h[i] = 0; T0l[i] = 0; }
  if (t < 96)  A12[t] = Aeq[t];
  if (t < 192) A12[96 + t] = A[t];
  __syncthreads();
  for (int idx = t; idx < 576; idx += 256) {
    int j = idx / 24, k = idx % 24;
    float s = (j == k) ? (1.0f + SIGMA_C + 2.0f * RHO_C) : 0.0f;
    for (int r = 0; r < 12; ++r) s += RHO_C * A12[r * 24 + j] * A12[r * 24 + k];
    Aug[j][k] = s;
    Aug[j][24 + k] = (j == k) ? 1.0f : 0.0f;
  }
  __syncthreads();
  for (int p = 0; p < 24; ++p) {
    float rp = 1.0f / Aug[p][p];
    if (t < 24) fac[t] = Aug[t][p];
    __syncthreads();
    if (t < 48) Aug[p][t] *= rp;
    __syncthreads();
    for (int idx = t; idx < 24 * 48; idx += 256) {
      int r = idx / 48, c = idx % 48;
      if (r != p) Aug[r][c] -= fac[r] * Aug[p][c];
    }
    __syncthreads();
  }
  auto splitStore = [](ushort* hp, ushort* lp, int i, float v) {
    ushort hs = f2bf(v);
    float hf = __uint_as_float(((uint)hs) << 16);
    ushort ls = f2bf(v - hf);
    hp[i] = hs; lp[i] = ls;
  };
  for (int idx = t; idx < 24 * 36; idx += 256) {
    int n = idx / 36, k = idx % 36;
    float v;
    if (k < 24) v = 2.0f * Aug[n][24 + k];
    else {
      v = 0.0f;
      for (int j = 0; j < 24; ++j) v += Aug[n][24 + j] * A12[(k - 24) * 24 + j];
    }
    Tx[n][k] = v;
    splitStore(Th, Tl, n * 64 + k, v);
  }
  __syncthreads();
  for (int idx = t; idx < 12 * 36; idx += 256) {
    int m = idx / 36, k = idx % 36;
    float v = 0.0f;
    for (int j = 0; j < 24; ++j) v += A12[m * 24 + j] * Tx[j][k];
    splitStore(Th, Tl, (24 + m) * 64 + k, v);
  }
  for (int idx = t; idx < 36 * 24; idx += 256) {
    int n = idx / 24, k = idx % 24;
    float v;
    if (n < 24) v = Aug[n][24 + k];
    else {
      v = 0.0f;
      for (int j = 0; j < 24; ++j) v += A12[(n - 24) * 24 + j] * Aug[j][24 + k];
    }
    splitStore(T0h, T0l, n * 32 + k, v);
  }
  if (t < 48) {
    float lv, uv;
    if (t < 24)      { lv = lb[t]; uv = ub[t]; }
    else if (t < 28) { lv = beq[t - 24]; uv = lv; }
    else if (t < 36) { lv = -1e30f; uv = b[t - 28]; }
    else             { lv = -1e30f; uv = 1e30f; }
    blp[t] = lv; bup[t] = uv;
  }
}

// Fused prep: [0,nConv) convert | [+512) W1T | [+1024) W2T | [+32) W3T | [1) setup
__global__ void prep_all(
    const float* __restrict__ state, ushort* __restrict__ stateB, int n4,
    const float* __restrict__ W1, ushort* __restrict__ W1T,
    const float* __restrict__ W2, ushort* __restrict__ W2T,
    const float* __restrict__ W3, ushort* __restrict__ W3T,
    const float* __restrict__ Aeq, const float* __restrict__ beq,
    const float* __restrict__ A, const float* __restrict__ b,
    const float* __restrict__ ub, const float* __restrict__ lb,
    ushort* __restrict__ Th, ushort* __restrict__ Tl,
    ushort* __restrict__ T0h, ushort* __restrict__ T0l,
    float* __restrict__ blp, float* __restrict__ bup) {
  const int nConv = n4 >> 8;
  int bb = blockIdx.x;
  if (bb < nConv) {
    int i = bb * 256 + threadIdx.x;
    if (i < n4) {
      float4 v = ((const float4*)state)[i];
      uint2 p;
      p.x = (uint)f2bf(v.x) | ((uint)f2bf(v.y) << 16);
      p.y = (uint)f2bf(v.z) | ((uint)f2bf(v.w) << 16);
      ((uint2*)stateB)[i] = p;
    }
    return;
  }
  bb -= nConv;
  if (bb < 512)  { transpose_body(W1, W1T, 512, 1024, 1024, bb & 31, bb >> 5, threadIdx.x); return; }
  bb -= 512;
  if (bb < 1024) { transpose_body(W2, W2T, 1024, 1024, 1024, bb & 31, bb >> 5, threadIdx.x); return; }
  bb -= 1024;
  if (bb < 32)   { transpose_body(W3, W3T, 1024, 24, 32, 0, bb, threadIdx.x); return; }
  setup_body(Aeq, beq, A, b, ub, lb, Th, Tl, T0h, T0l, blp, bup, threadIdx.x);
}

// ---------------------------------------------------------------------------
// bf16 GEMM, C = A[M,K] * Bt[N,K]^T — m97-style staging (skinny final layer).
// ---------------------------------------------------------------------------
template<int BM, int BN, int WM, int WN, int TM, int TN, int MODE>
__global__ __launch_bounds__(256) void gemm_bt(
    const ushort* __restrict__ A, const ushort* __restrict__ Bt,
    const float* __restrict__ bias, void* __restrict__ Cout_,
    int K, int ldc, int nvalid) {
  __shared__ char lds[(BM + BN) * 64];
  char* ldsA = lds;
  char* ldsB = lds + BM * 64;

  const int tid = threadIdx.x;
  const int wave = tid >> 6;
  const int lane = tid & 63;
  const int blockM = blockIdx.y * BM;
  const int blockN = blockIdx.x * BN;
  const int wm = (wave / WN) * (TM * 16);
  const int wn = (wave % WN) * (TN * 16);

  f32x4 acc[TM][TN] = {};

  const int l15 = lane & 15;
  const int kq = lane >> 4;
  constexpr int AI = BM / 16;
  constexpr int TOT = (BM + BN) / 16;
  const int srow = lane >> 2;
  const int kb = (lane & 3) ^ ((srow >> 1) & 3);

  for (int k0 = 0; k0 < K; k0 += 32) {
    for (int inst = wave; inst < TOT; inst += 4) {
      const bool isA = inst < AI;
      const int i = isA ? inst : inst - AI;
      const ushort* gp = (isA ? A : Bt)
          + (long)((isA ? blockM : blockN) + i * 16 + srow) * K + (k0 + kb * 8);
      char* lp = (isA ? ldsA : ldsB) + i * 1024;
      gload_lds16(gp, lp);
    }
    __syncthreads();

    bf16x8 af[TM], bfr[TN];
#pragma unroll
    for (int i = 0; i < TM; ++i) {
      int r = wm + i * 16 + l15;
      int ch = kq ^ ((r >> 1) & 3);
      af[i] = *(const bf16x8*)(ldsA + r * 64 + ch * 16);
    }
#pragma unroll
    for (int j = 0; j < TN; ++j) {
      int r = wn + j * 16 + l15;
      int ch = kq ^ ((r >> 1) & 3);
      bfr[j] = *(const bf16x8*)(ldsB + r * 64 + ch * 16);
    }
#pragma unroll
    for (int i = 0; i < TM; ++i)
#pragma unroll
      for (int j = 0; j < TN; ++j)
        acc[i][j] = __builtin_amdgcn_mfma_f32_16x16x32_bf16(af[i], bfr[j], acc[i][j], 0, 0, 0);
    __syncthreads();
  }

  const int ro = lane >> 4;
#pragma unroll
  for (int i = 0; i < TM; ++i) {
#pragma unroll
    for (int j = 0; j < TN; ++j) {
      const int col = blockN + wn + j * 16 + l15;
      float bv;
      if (MODE == 0) bv = bias[col];
      else bv = (col < nvalid) ? bias[col] : 0.0f;
#pragma unroll
      for (int r = 0; r < 4; ++r) {
        const int row = blockM + wm + i * 16 + ro * 4 + r;
        float v = acc[i][j][r] + bv;
        if (MODE == 0) {
          v = fmaxf(v, 0.0f);
          ((ushort*)Cout_)[(long)row * ldc + col] = f2bf(v);
        } else {
          if (col < nvalid) ((float*)Cout_)[(long)row * ldc + col] = v;
        }
      }
    }
  }
}

// ---------------------------------------------------------------------------
// 256x256 8-phase bf16 GEMM (T1+T2+T3+T4+T5) — unchanged.
// ---------------------------------------------------------------------------
#define GEMM8P_QUAD(MI0, NJ0)                                                 \
  _Pragma("unroll") for (int mi_ = 0; mi_ < 4; ++mi_)                         \
  _Pragma("unroll") for (int nj_ = 0; nj_ < 2; ++nj_)                         \
  _Pragma("unroll") for (int kk_ = 0; kk_ < 2; ++kk_)                         \
    acc[(MI0) + mi_][(NJ0) + nj_] = __builtin_amdgcn_mfma_f32_16x16x32_bf16(  \
        aF[mi_][kk_], bF[(NJ0) + nj_][kk_], acc[(MI0) + mi_][(NJ0) + nj_],    \
        0, 0, 0);

#define GEMM8P_SYNC_PRE()                              \
  __builtin_amdgcn_s_barrier();                        \
  asm volatile("s_waitcnt lgkmcnt(0)" ::: "memory");   \
  __builtin_amdgcn_sched_barrier(0);                   \
  __builtin_amdgcn_s_setprio(1);

#define GEMM8P_SYNC_POST()                             \
  __builtin_amdgcn_s_setprio(0);                       \
  __builtin_amdgcn_s_barrier();

__global__ __launch_bounds__(512, 2) void gemm8p(
    const ushort* __restrict__ A, const ushort* __restrict__ Bt,
    const float* __restrict__ bias, ushort* __restrict__ Cout,
    int K, int ldc, int nblk_n) {
  __shared__ __align__(16) char ldsc[131072];   // [2 buf][A 32K | B 32K]

  const int nwg = gridDim.x;
  const int bid = blockIdx.x;
  const int swz = (bid & 7) * (nwg >> 3) + (bid >> 3);
  const int blockM = (swz / nblk_n) * 256;
  const int blockN = (swz % nblk_n) * 256;

  const int tid = threadIdx.x;
  const int wave = tid >> 6;
  const int lane = tid & 63;
  const int l15 = lane & 15;
  const int q = lane >> 4;
  const int wm = (wave >> 2) * 128;
  const int wn = (wave & 3) * 64;
  const int nt = K >> 6;

  f32x4 acc[8][4] = {};

  auto stage = [&](int ts, int h) {
    if (ts >= nt) return;
    char* base = ldsc + ((ts & 1) << 16) + (h << 14);
#pragma unroll
    for (int j = 0; j < 2; ++j) {
      const int idx = wave * 64 + j * 512 + lane;
      const int row = idx >> 3;
      const int cs = (idx & 7) ^ (row & 7);
      const ushort* gp =
          (h < 2 ? A + (long)(blockM + ((h & 1) << 7) + row) * K
                 : Bt + (long)(blockN + ((h & 1) << 7) + row) * K)
          + (ts << 6) + cs * 8;
      gload_lds16(gp, base + ((wave * 64 + j * 512) << 4));
    }
  };
  auto dsA = [&](int cb, int mi, int kk) {
    const int r = wm + mi * 16 + l15;
    const int cs = (kk * 4 + q) ^ (r & 7);
    return *(const bf16x8*)(ldsc + (cb << 16) + r * 128 + cs * 16);
  };
  auto dsB = [&](int cb, int nj, int kk) {
    const int r = wn + nj * 16 + l15;
    const int cs = (kk * 4 + q) ^ (r & 7);
    return *(const bf16x8*)(ldsc + (cb << 16) + 32768 + r * 128 + cs * 16);
  };

  stage(0, 0); stage(0, 1); stage(0, 2); stage(0, 3);
  stage(1, 0);
  asm volatile("s_waitcnt vmcnt(2)" ::: "memory");
  __builtin_amdgcn_s_barrier();

  bf16x8 aF[4][2], bF[4][2];
#pragma unroll 1
  for (int t = 0; t < nt; ++t) {
    const int cb = t & 1;
#pragma unroll
    for (int mi = 0; mi < 4; ++mi)
#pragma unroll
      for (int kk = 0; kk < 2; ++kk) aF[mi][kk] = dsA(cb, mi, kk);
#pragma unroll
    for (int nj = 0; nj < 2; ++nj)
#pragma unroll
      for (int kk = 0; kk < 2; ++kk) bF[nj][kk] = dsB(cb, nj, kk);
    stage(t + 1, 1);
    GEMM8P_SYNC_PRE();
    GEMM8P_QUAD(0, 0);
    GEMM8P_SYNC_POST();
#pragma unroll
    for (int nj = 2; nj < 4; ++nj)
#pragma unroll
      for (int kk = 0; kk < 2; ++kk) bF[nj][kk] = dsB(cb, nj, kk);
    stage(t + 1, 2);
    GEMM8P_SYNC_PRE();
    GEMM8P_QUAD(0, 2);
    GEMM8P_SYNC_POST();
#pragma unroll
    for (int mi = 0; mi < 4; ++mi)
#pragma unroll
      for (int kk = 0; kk < 2; ++kk) aF[mi][kk] = dsA(cb, 4 + mi, kk);
    stage(t + 1, 3);
    GEMM8P_SYNC_PRE();
    GEMM8P_QUAD(4, 2);
    GEMM8P_SYNC_POST();
    stage(t + 2, 0);
    if (t + 2 < nt) { asm volatile("s_waitcnt vmcnt(2)" ::: "memory"); }
    else            { asm volatile("s_waitcnt vmcnt(0)" ::: "memory"); }
    __builtin_amdgcn_s_barrier();
    __builtin_amdgcn_s_setprio(1);
    GEMM8P_QUAD(4, 0);
    GEMM8P_SYNC_POST();
  }

#pragma unroll
  for (int mi = 0; mi < 8; ++mi) {
#pragma unroll
    for (int nj = 0; nj < 4; ++nj) {
      const int col = blockN + wn + nj * 16 + l15;
      const float bv = bias[col];
#pragma unroll
      for (int r = 0; r < 4; ++r) {
        const int row = blockM + wm + mi * 16 + q * 4 + r;
        float v = acc[mi][nj][r] + bv;
        v = fmaxf(v, 0.0f);
        Cout[(long)row * ldc + col] = f2bf(v);
      }
    }
  }
}

// ---------------------------------------------------------------------------
// ADMM via MFMA (round-7: 3-wave split, one output tile per wave).
// r1-r6 evidence: every 1-wave-per-row-group variant = 1340-1940 cy/iter vs
// ~400 cy critical-path estimate — per-wave stall that 1 wave/SIMD cannot
// hide; r6's duplicate-wave trick failed because duplicates are phase-
// correlated. Fix: REAL 3x occupancy by splitting the 36x36 op into its 3
// independent 16-row output tiles, one WAVE each (block=192thr, grid=1024,
// 3072 waves = 3/SIMD from different blocks -> decorrelated).
// Per wave/iter: clip+pack own 4-elem tile (~40 VALU), 2 ds_write_b64,
// one __syncthreads (u is cross-wave), 4 ds_read_b128, 6 MFMAs in TWO
// 3-deep chains (vs 18 in 6-deep). u double-buffered (9KB LDS): write ->
// barrier -> read is race-free; buffer re-write is a full barrier after its
// last read (parity alternates). Pair algebra identical to r6 (verified):
// pair P = elements {2P,2P+1}; wave t writes P=8t+2q+{0,1}; read dword m at
// P=16c+4q+m -> k=32c+8q+j. Bank census unchanged (4 dw/bank wr, 8 rd).
// Zero-init both buffers then barrier (pads P=24..31 stay zero forever).
// Epilogue: X_100 = base + T*u_99; wave 2 only produces u_2, waves 0/1 store.
// ---------------------------------------------------------------------------
__global__ __launch_bounds__(192) void admm_mfma(
    const float* __restrict__ raw,
    const ushort* __restrict__ Th, const ushort* __restrict__ Tl,
    const ushort* __restrict__ T0h, const ushort* __restrict__ T0l,
    const float* __restrict__ blp, const float* __restrict__ bup,
    float* __restrict__ outp) {
  __shared__ __align__(16) float U2[2 * 1152];  // [buf][hi 576 dw | lo 576 dw]
  const int tid = threadIdx.x, wv = tid >> 6, lane = tid & 63;
  const int l15 = lane & 15, q = lane >> 4;
  const long rowbase = (long)blockIdx.x * 16;

  // zero both buffers once (pads stay zero); barrier before first u-write
  for (int i = tid; i < 2304; i += 192) U2[i] = 0.0f;

  uint* uw = (uint*)U2;
  const int wofs = 36 * l15 + 2 * q + 8 * wv;   // own-tile write dword offset
  const int rofs = 36 * l15 + 4 * q;            // read dword offset

  // bounds for own tile: n = 16*wv + 4q + r
  const f32x4 bl = *(const f32x4*)(blp + 16 * wv + 4 * q);
  const f32x4 bu = *(const f32x4*)(bup + 16 * wv + 4 * q);

  // ---- peel: base = W_1 = T0 * q^T (own tile only) ------------------------
  f32x4 W, base;
  {
    bf16x8 t0h = *(const bf16x8*)(T0h + (16 * wv + l15) * 32 + q * 8);
    bf16x8 t0l = *(const bf16x8*)(T0l + (16 * wv + l15) * 32 + q * 8);
    float qa[8];
    if (q < 3) {
      const float* rp = raw + (rowbase + l15) * 24 + q * 8;
      float4 v0 = *(const float4*)rp;
      float4 v1 = *(const float4*)(rp + 4);
      qa[0] = v0.x; qa[1] = v0.y; qa[2] = v0.z; qa[3] = v0.w;
      qa[4] = v1.x; qa[5] = v1.y; qa[6] = v1.z; qa[7] = v1.w;
    } else {
#pragma unroll
      for (int j = 0; j < 8; ++j) qa[j] = 0.0f;
    }
    bf16x8 qhi, qlo;
    splitPack(qa, qhi, qlo);
    f32x4 acc = {0.0f, 0.0f, 0.0f, 0.0f};
    acc = __builtin_amdgcn_mfma_f32_16x16x32_bf16(t0h, qhi, acc, 0, 0, 0);
    acc = __builtin_amdgcn_mfma_f32_16x16x32_bf16(t0h, qlo, acc, 0, 0, 0);
    acc = __builtin_amdgcn_mfma_f32_16x16x32_bf16(t0l, qhi, acc, 0, 0, 0);
    base = acc; W = acc;
  }

  // ---- T A-fragments, own tile: th_c = T[16wv+l15][32c+8q+j] --------------
  const bf16x8 th0 = *(const bf16x8*)(Th + (16 * wv + l15) * 64 + q * 8);
  const bf16x8 th1 = *(const bf16x8*)(Th + (16 * wv + l15) * 64 + 32 + q * 8);
  const bf16x8 tl0 = *(const bf16x8*)(Tl + (16 * wv + l15) * 64 + q * 8);
  const bf16x8 tl1 = *(const bf16x8*)(Tl + (16 * wv + l15) * 64 + 32 + q * 8);

  __syncthreads();   // zero-init visible to all before first u-write

  const f32x4 z4 = {0.0f, 0.0f, 0.0f, 0.0f};

#pragma unroll 1
  for (int it = 2; it < ADMM_ITERS; ++it) {   // 98 updates: W_1 -> W_99
    const int db = (it & 1) ? 1152 : 0;
    f32x4 C, u_;
#pragma unroll
    for (int r = 0; r < 4; ++r) {
      float w_ = W[r];
      float z_ = fminf(fmaxf(w_, bl[r]), bu[r]);
      float yy_ = w_ - z_;
      u_[r] = z_ - yy_;                  // = 2z - w
      C[r] = base[r] + yy_;
    }
    uint h0, h1, l0, l1;
    packPairs(u_, h0, h1, l0, l1);
    uint* wp = uw + db + wofs;
    wp[0] = h0; wp[1] = h1; wp[576] = l0; wp[577] = l1;
    __syncthreads();
    const float* rp = U2 + db + rofs;
    bf16x8 uh0 = *(const bf16x8*)rp;
    bf16x8 uh1 = *(const bf16x8*)(rp + 16);
    bf16x8 ul0 = *(const bf16x8*)(rp + 576);
    bf16x8 ul1 = *(const bf16x8*)(rp + 592);
    f32x4 a = C, b = z4;
    a = __builtin_amdgcn_mfma_f32_16x16x32_bf16(th0, uh0, a, 0, 0, 0);
    b = __builtin_amdgcn_mfma_f32_16x16x32_bf16(th1, uh1, b, 0, 0, 0);
    a = __builtin_amdgcn_mfma_f32_16x16x32_bf16(th0, ul0, a, 0, 0, 0);
    b = __builtin_amdgcn_mfma_f32_16x16x32_bf16(th1, ul1, b, 0, 0, 0);
    a = __builtin_amdgcn_mfma_f32_16x16x32_bf16(tl0, uh0, a, 0, 0, 0);
    b = __builtin_amdgcn_mfma_f32_16x16x32_bf16(tl1, uh1, b, 0, 0, 0);
    W = a + b;
  }

  // ---- epilogue: X_100 = base + T*u_99 (yy cancels); waves 0,1 store ------
  {
    const int db = (ADMM_ITERS & 1) ? 1152 : 0;
    f32x4 u_;
#pragma unroll
    for (int r = 0; r < 4; ++r) {
      float w_ = W[r];
      float z_ = fminf(fmaxf(w_, bl[r]), bu[r]);
      u_[r] = z_ - (w_ - z_);
    }
    uint h0, h1, l0, l1;
    packPairs(u_, h0, h1, l0, l1);
    uint* wp = uw + db + wofs;
    wp[0] = h0; wp[1] = h1; wp[576] = l0; wp[577] = l1;
    __syncthreads();
    if (wv < 2) {
      const float* rp = U2 + db + rofs;
      bf16x8 uh0 = *(const bf16x8*)rp;
      bf16x8 uh1 = *(const bf16x8*)(rp + 16);
      bf16x8 ul0 = *(const bf16x8*)(rp + 576);
      bf16x8 ul1 = *(const bf16x8*)(rp + 592);
      f32x4 a = base, b = z4;
      a = __builtin_amdgcn_mfma_f32_16x16x32_bf16(th0, uh0, a, 0, 0, 0);
      b = __builtin_amdgcn_mfma_f32_16x16x32_bf16(th1, uh1, b, 0, 0, 0);
      a = __builtin_amdgcn_mfma_f32_16x16x32_bf16(th0, ul0, a, 0, 0, 0);
      b = __builtin_amdgcn_mfma_f32_16x16x32_bf16(th1, ul1, b, 0, 0, 0);
      a = __builtin_amdgcn_mfma_f32_16x16x32_bf16(tl0, uh0, a, 0, 0, 0);
      b = __builtin_amdgcn_mfma_f32_16x16x32_bf16(tl1, uh1, b, 0, 0, 0);
      f32x4 X = a + b;
      if (wv == 0) {
        *(f32x4*)(outp + (rowbase + l15) * 24 + 4 * q) = X;
      } else if (q < 2) {
        *(f32x4*)(outp + (rowbase + l15) * 24 + 16 + 4 * q) = X;
      }
    }
  }
}

// ---------------------------------------------------------------------------
extern "C" void kernel_launch(void* const* d_in, const int* in_sizes, int n_in,
                              void* d_out, int out_size, void* d_ws, size_t ws_size,
                              hipStream_t stream) {
  const float* state = (const float*)d_in[0];
  const float* Aeq   = (const float*)d_in[1];
  const float* beq   = (const float*)d_in[2];
  const float* Ain   = (const float*)d_in[3];
  const float* bin   = (const float*)d_in[4];
  const float* ub    = (const float*)d_in[5];
  const float* lb    = (const float*)d_in[6];
  const float* W1    = (const float*)d_in[7];
  const float* b1    = (const float*)d_in[8];
  const float* W2    = (const float*)d_in[9];
  const float* b2    = (const float*)d_in[10];
  const float* W3    = (const float*)d_in[11];
  const float* b3    = (const float*)d_in[12];

  const int Bn = in_sizes[0] / 512;            // 16384
  char* ws = (char*)d_ws;
  ushort* stateB = (ushort*)(ws + 0);          // 16384x512 bf16  (16 MB)
  ushort* W1T    = (ushort*)(ws + 16777216);   // 1024x512        (1 MB)
  ushort* W2T    = (ushort*)(ws + 17825792);   // 1024x1024       (2 MB)
  ushort* W3T    = (ushort*)(ws + 19922944);   // 32x1024 (rows>=24 zero)
  ushort* Th     = (ushort*)(ws + 19993600);   // 48x64 bf16 hi
  ushort* Tl     = (ushort*)(ws + 19999744);   // 48x64 bf16 lo
  ushort* T0h    = (ushort*)(ws + 20005888);   // 48x32 bf16 hi
  ushort* T0l    = (ushort*)(ws + 20008960);   // 48x32 bf16 lo
  float*  blp    = (float*) (ws + 20012032);   // 48
  float*  bup    = (float*) (ws + 20012224);   // 48
  ushort* H1     = (ushort*)(ws + 21565440);   // 16384x1024 bf16 (32 MB)
  ushort* H2     = (ushort*)(ws + 55119872);   // 16384x1024 bf16 (32 MB)
  float*  rawb   = (float*)d_out;              // gemm3 out = admm in (in-place)

  const int n4 = (Bn * 512) / 4;
  const int nConv = n4 / 256;                  // 8192
  const int nPrep = nConv + 512 + 1024 + 32 + 1;
  prep_all<<<nPrep, 256, 0, stream>>>(state, stateB, n4, W1, W1T, W2, W2T, W3, W3T,
                                      Aeq, beq, Ain, bin, ub, lb,
                                      Th, Tl, T0h, T0l, blp, bup);

  const int nblkN = 1024 / 256;                // 4
  const int nwg = (Bn / 256) * nblkN;          // 256 (div by 8 -> swizzle ok)
  gemm8p<<<nwg, 512, 0, stream>>>(stateB, W1T, b1, H1, 512, 1024, nblkN);
  gemm8p<<<nwg, 512, 0, stream>>>(H1, W2T, b2, H2, 1024, 1024, nblkN);
  gemm_bt<64, 32, 4, 1, 1, 2, 1><<<dim3(1, Bn / 64), 256, 0, stream>>>(
      H2, W3T, b3, rawb, 1024, 24, 24);

  // one 16-row group per block, 3 waves = 3 output tiles -> 3 waves/SIMD
  admm_mfma<<<Bn / 16, 192, 0, stream>>>(rawb, Th, Tl, T0h, T0l, blp, bup,
                                         (float*)d_out);
}